// Round 1
// 195.517 us; speedup vs baseline: 1.0163x; 1.0163x over previous
//
#include <hip/hip_runtime.h>
#include <math.h>

#define N_TOK   16384
#define EDIM    64
#define NE      4096
#define NSLICE  16                       /* 16 slices x 256 codes */
#define TPB     256
#define ZQ_OFF  1
#define IDX_OFF (1 + N_TOK * EDIM)       /* 1048577 */
#define PERP_OFF (IDX_OFF + N_TOK)       /* 1064961 */

typedef unsigned long long u64;

// ---------------------------------------------------------------------------
// Kernel A: per-row squared norms replicating numpy pairwise_sum (n=64 path:
// 8 accumulators stride 8, then ((r0+r1)+(r2+r3))+((r4+r5)+(r6+r7))),
// with products ROUNDED before summation (contract off). Also zero-inits
// the histogram and loss accumulator in ws. (unchanged)
// ---------------------------------------------------------------------------
__global__ __launch_bounds__(256) void norms_zero_kernel(
    const float* __restrict__ z, const float* __restrict__ cb,
    float* __restrict__ nz, float* __restrict__ ne,
    int* __restrict__ hist, float* __restrict__ lossAcc) {
#pragma clang fp contract(off)
    int i = blockIdx.x * 256 + threadIdx.x;
    if (i < NE) hist[i] = 0;
    if (i == 0) lossAcc[0] = 0.0f;
    const float* row;
    float* dst;
    if (i < N_TOK)            { row = z  + (size_t)i * EDIM;           dst = nz + i; }
    else if (i < N_TOK + NE)  { row = cb + (size_t)(i - N_TOK) * EDIM; dst = ne + (i - N_TOK); }
    else return;

    float r[8];
#pragma unroll
    for (int j = 0; j < 8; ++j) { float v = row[j]; r[j] = v * v; }
#pragma unroll
    for (int b = 8; b < 64; b += 8) {
#pragma unroll
        for (int j = 0; j < 8; ++j) { float v = row[b + j]; r[j] = r[j] + v * v; }
    }
    dst[0] = ((r[0] + r[1]) + (r[2] + r[3])) + ((r[4] + r[5]) + (r[6] + r[7]));
}

// ---------------------------------------------------------------------------
// Kernel B (rewritten): GEMM-style register tiling. Previous version was
// LDS-pipe-bound: 32 broadcast ds_read_b128 per 256 FMAs (r=8) -> ~10.4
// cyc/read * 32768 reads/CU == the whole 142us. New structure: block tile
// 128 tokens x 128 codes, thread tile 8x8 (64 fp32 acc), both operands in
// LDS -> 16 ds_read_b128 per 256 FMAs (r=16), halving LDS-pipe demand.
//
// LDS layout (both tiles): float4 tile[row=q*8+g][col], col = g' ^ (row&15)
// XOR-swizzle; reads within a row hit 16 distinct bank-quads 2-way (free),
// staging writes spread across all 8 quads. zt+ct = exactly 64 KB -> 2
// blocks/CU (8 waves/CU) at launch_bounds(256,2).
//
// Numerics: per-(token,code) dot is the SAME sequential q-ascending,
// x->w-ascending fp32 FMA chain as the passing kernel (bits identical ->
// ties exact). d = fma(-2, dot, nz+ne[k]); argmin packed (d_bits<<32)|k,
// u64 min == first-index tie-break (d>0 so float bits monotone). Block
// reduces 16 code-group candidates per token; part layout unchanged.
// ---------------------------------------------------------------------------
__global__ __launch_bounds__(256, 2) void dist_argmin_kernel(
    const float* __restrict__ z, const float* __restrict__ cb,
    const float* __restrict__ nz, const float* __restrict__ ne,
    u64* __restrict__ part) {
    __shared__ float4 zt[2048];          // 32 KB: z tile, 128 tokens x 64 dims
    __shared__ float4 ct[2048];          // 32 KB: code tile, 128 codes x 64 dims
    const int tid   = threadIdx.x;
    const int tg    = tid & 15;          // token group (8 tokens)
    const int cg    = tid >> 4;          // code group (8 codes)
    const int bx    = blockIdx.x;
    const int slice = blockIdx.y;
    const int tok0  = bx * 128;

    // ---- stage z tile (transposed + swizzled), 8 contiguous float4/thread
    {
        const float4* zp = (const float4*)z + (size_t)tok0 * 16;
#pragma unroll
        for (int r = 0; r < 8; ++r) {
            const int f   = tid * 8 + r;         // 0..2047
            const int tl  = f >> 4;              // local token
            const int q   = f & 15;              // dim-group
            const int row = q * 8 + (tl & 7);
            const int col = (tl >> 3) ^ (row & 15);
            zt[row * 16 + col] = zp[f];
        }
    }

    float tnz[8];
#pragma unroll
    for (int i = 0; i < 8; ++i) tnz[i] = nz[tok0 + tg * 8 + i];

    u64 best[8];
#pragma unroll
    for (int i = 0; i < 8; ++i) best[i] = ~0ull;

#pragma unroll 1
    for (int c = 0; c < 2; ++c) {
        const int kbase = slice * 256 + c * 128;
        {
            const float4* cp = (const float4*)cb + (size_t)kbase * 16;
#pragma unroll
            for (int r = 0; r < 8; ++r) {
                const int f   = tid * 8 + r;
                const int lc  = f >> 4;          // local code
                const int q   = f & 15;
                const int row = q * 8 + (lc & 7);
                const int col = (lc >> 3) ^ (row & 15);
                ct[row * 16 + col] = cp[f];
            }
        }
        float sne[8];
#pragma unroll
        for (int j = 0; j < 8; ++j) sne[j] = ne[kbase + cg * 8 + j];
        __syncthreads();

        float acc[8][8];
#pragma unroll
        for (int i = 0; i < 8; ++i)
#pragma unroll
            for (int j = 0; j < 8; ++j) acc[i][j] = 0.0f;

#pragma unroll
        for (int q = 0; q < 16; ++q) {
            float4 zf[8], cf[8];
#pragma unroll
            for (int i = 0; i < 8; ++i) {
                const int row = q * 8 + i;
                zf[i] = zt[row * 16 + (tg ^ (row & 15))];
            }
#pragma unroll
            for (int j = 0; j < 8; ++j) {
                const int row = q * 8 + j;
                cf[j] = ct[row * 16 + (cg ^ (row & 15))];
            }
#pragma unroll
            for (int i = 0; i < 8; ++i)
#pragma unroll
                for (int j = 0; j < 8; ++j) {
                    acc[i][j] = __builtin_fmaf(zf[i].x, cf[j].x, acc[i][j]);
                    acc[i][j] = __builtin_fmaf(zf[i].y, cf[j].y, acc[i][j]);
                    acc[i][j] = __builtin_fmaf(zf[i].z, cf[j].z, acc[i][j]);
                    acc[i][j] = __builtin_fmaf(zf[i].w, cf[j].w, acc[i][j]);
                }
        }

#pragma unroll
        for (int i = 0; i < 8; ++i)
#pragma unroll
            for (int j = 0; j < 8; ++j) {
                const float d = __builtin_fmaf(-2.0f, acc[i][j], tnz[i] + sne[j]);
                const u64 p = ((u64)__float_as_uint(d) << 32)
                            | (u64)(kbase + cg * 8 + j);
                if (p < best[i]) best[i] = p;
            }
        __syncthreads();   // protect ct (next stage) / red overlay
    }

    // ---- block-level reduce across the 16 code groups (overlay on ct)
    u64* red = (u64*)ct;
#pragma unroll
    for (int i = 0; i < 8; ++i) red[cg * 128 + tg * 8 + i] = best[i];
    __syncthreads();
    if (tid < 128) {
        u64 b = red[tid];
#pragma unroll
        for (int s = 1; s < 16; ++s) {
            const u64 p = red[s * 128 + tid];
            if (p < b) b = p;
        }
        part[(size_t)slice * N_TOK + tok0 + tid] = b;
    }
}

// ---------------------------------------------------------------------------
// Kernel C: combine 16 slice-partials (u64 min keeps first-index tie-break),
// write idx as float, histogram, gather z_q, write z_q_st = z + (z_q - z)
// exactly as the reference computes it, and accumulate sum((z_q - z)^2).
// (unchanged)
// ---------------------------------------------------------------------------
__global__ __launch_bounds__(256) void reduce_gather_kernel(
    const float* __restrict__ z, const float* __restrict__ cb,
    const u64* __restrict__ part, int* __restrict__ hist,
    float* __restrict__ lossAcc, float* __restrict__ out) {
    const int t = blockIdx.x * 256 + threadIdx.x;
    u64 best = part[t];
#pragma unroll
    for (int s = 1; s < NSLICE; ++s) {
        u64 p = part[(size_t)s * N_TOK + t];
        if (p < best) best = p;
    }
    const int idx = (int)(best & 0xFFFFFFFFull);
    out[IDX_OFF + t] = (float)idx;
    atomicAdd(&hist[idx], 1);

    const float4* ev = (const float4*)(cb + (size_t)idx * EDIM);
    const float4* zv = (const float4*)(z + (size_t)t * EDIM);
    float* o = out + ZQ_OFF + (size_t)t * EDIM;  // out+1: only 4B-aligned -> scalar stores
    float acc = 0.0f;
#pragma unroll
    for (int j = 0; j < 16; ++j) {
        float4 e = ev[j], zz = zv[j];
        float d;
        d = e.x - zz.x; o[4 * j + 0] = zz.x + d; acc = __builtin_fmaf(d, d, acc);
        d = e.y - zz.y; o[4 * j + 1] = zz.y + d; acc = __builtin_fmaf(d, d, acc);
        d = e.z - zz.z; o[4 * j + 2] = zz.z + d; acc = __builtin_fmaf(d, d, acc);
        d = e.w - zz.w; o[4 * j + 3] = zz.w + d; acc = __builtin_fmaf(d, d, acc);
    }
    __shared__ float red[256];
    red[threadIdx.x] = acc;
    __syncthreads();
    for (int s = 128; s > 0; s >>= 1) {
        if (threadIdx.x < s) red[threadIdx.x] += red[threadIdx.x + s];
        __syncthreads();
    }
    if (threadIdx.x == 0) atomicAdd(lossAcc, red[0]);
}

// ---------------------------------------------------------------------------
// Kernel D: perplexity from histogram + loss finalize. (unchanged)
// ---------------------------------------------------------------------------
__global__ __launch_bounds__(256) void finalize_kernel(
    const int* __restrict__ hist, const float* __restrict__ lossAcc,
    float* __restrict__ out) {
    __shared__ float red[256];
    float acc = 0.0f;
    for (int i = threadIdx.x; i < NE; i += 256) {
        float e = (float)hist[i] * (1.0f / 16384.0f);  // exact /n_tokens
        acc += e * logf(e + 1e-10f);
    }
    red[threadIdx.x] = acc;
    __syncthreads();
    for (int s = 128; s > 0; s >>= 1) {
        if (threadIdx.x < s) red[threadIdx.x] += red[threadIdx.x + s];
        __syncthreads();
    }
    if (threadIdx.x == 0) {
        out[PERP_OFF] = expf(-red[0]);
        float m = lossAcc[0] * (1.0f / 1048576.0f);    // exact /B*T*E
        out[0] = m + 0.25f * m;
    }
}

extern "C" void kernel_launch(void* const* d_in, const int* in_sizes, int n_in,
                              void* d_out, int out_size, void* d_ws, size_t ws_size,
                              hipStream_t stream) {
    const float* z  = (const float*)d_in[0];
    const float* cb = (const float*)d_in[1];
    float* out = (float*)d_out;

    char* ws = (char*)d_ws;
    u64*   part    = (u64*)ws;                                  // 2 MB
    float* nz      = (float*)(ws + (size_t)NSLICE * N_TOK * 8); // 64 KB
    float* ne      = nz + N_TOK;                                // 16 KB
    int*   hist    = (int*)(ne + NE);                           // 16 KB
    float* lossAcc = (float*)(hist + NE);                       // 4 B

    hipLaunchKernelGGL(norms_zero_kernel, dim3(80), dim3(256), 0, stream,
                       z, cb, nz, ne, hist, lossAcc);
    hipLaunchKernelGGL(dist_argmin_kernel,
                       dim3(N_TOK / 128, NSLICE), dim3(TPB), 0, stream,
                       z, cb, nz, ne, part);
    hipLaunchKernelGGL(reduce_gather_kernel, dim3(64), dim3(256), 0, stream,
                       z, cb, part, hist, lossAcc, out);
    hipLaunchKernelGGL(finalize_kernel, dim3(1), dim3(256), 0, stream,
                       hist, lossAcc, out);
}